// Round 5
// baseline (277.962 us; speedup 1.0000x reference)
//
#include <hip/hip_runtime.h>

// Conv2d 3x3 valid, C_in=8, C_out=8, H=W=2048, fp32.
// x: (8, 2048, 2048), weight: (8, 8, 3, 3), out: (8, 2046, 2046).
//
// v3: v2 tile (4w x 2h x 8co, vertical register reuse) + explicit depth-1
// software pipeline across ci: two named register buffers A/B, ci unrolled
// by 2 inside a runtime loop of 4 (body ~9.6KB, I$-resident). Loads for
// ci+1 are issued BEFORE the 576-FMA block of ci and pinned with
// sched_barrier(0) so the scheduler can't sink them; each 1152-cycle FMA
// block hides the ~900-cycle global-load latency.
// (Rounds 3/4 were infra failures — resubmission of v3 unchanged.)

#define H_IN   2048
#define W_IN   2048
#define H_OUT  2046
#define W_OUT  2046
#define CIN    8
#define COUT   8

#define TPR 512            // thread-columns per row-group (4 px each)
#define NGROUPS 1023       // 2046 / 2 output rows per thread
#define PLANE ((size_t)H_IN * W_IN)

__device__ __forceinline__
void load_rows(float (&in)[4][6], const float* __restrict__ base, int ci, bool full) {
    #pragma unroll
    for (int r = 0; r < 4; ++r) {
        const float* p = base + (size_t)ci * PLANE + (size_t)r * W_IN;
        const float4 v4 = *reinterpret_cast<const float4*>(p);   // 16B aligned
        in[r][0] = v4.x; in[r][1] = v4.y; in[r][2] = v4.z; in[r][3] = v4.w;
        if (full) {
            const float2 v2 = *reinterpret_cast<const float2*>(p + 4);
            in[r][4] = v2.x; in[r][5] = v2.y;
        } else {
            in[r][4] = 0.0f; in[r][5] = 0.0f;   // tail tile: px 2,3 never stored
        }
    }
}

__device__ __forceinline__
void compute_ci(float (&acc)[2][COUT][4], const float (&in)[4][6],
                const float* __restrict__ w, int ci) {
    // input row r feeds output row 0 with kh=r (r<3), row 1 with kh=r-1 (r>=1)
    #pragma unroll
    for (int r = 0; r < 4; ++r) {
        #pragma unroll
        for (int co = 0; co < COUT; ++co) {
            #pragma unroll
            for (int kw = 0; kw < 3; ++kw) {
                if (r < 3) {
                    const float wt = w[((co * CIN + ci) * 3 + r) * 3 + kw];
                    #pragma unroll
                    for (int px = 0; px < 4; ++px)
                        acc[0][co][px] = fmaf(wt, in[r][kw + px], acc[0][co][px]);
                }
                if (r >= 1) {
                    const float wt = w[((co * CIN + ci) * 3 + (r - 1)) * 3 + kw];
                    #pragma unroll
                    for (int px = 0; px < 4; ++px)
                        acc[1][co][px] = fmaf(wt, in[r][kw + px], acc[1][co][px]);
                }
            }
        }
    }
}

__global__ __launch_bounds__(256)
void conv3x3_v3(const float* __restrict__ x,
                const float* __restrict__ w,
                float* __restrict__ out) {
    const int gtid = blockIdx.x * 256 + threadIdx.x;
    const int g  = gtid / TPR;          // row group (2 output rows)
    const int tw = gtid - g * TPR;
    const int oh = g * 2;
    const int ow = tw * 4;
    const bool full = (tw != TPR - 1);  // tail tile (ow=2044): 2 valid cols

    float acc[2][COUT][4];
    #pragma unroll
    for (int r = 0; r < 2; ++r)
        #pragma unroll
        for (int co = 0; co < COUT; ++co)
            #pragma unroll
            for (int p = 0; p < 4; ++p)
                acc[r][co][p] = 0.0f;

    const float* base = x + (size_t)oh * W_IN + ow;

    float A[4][6], B[4][6];
    load_rows(A, base, 0, full);

    #pragma unroll 1
    for (int k = 0; k < CIN / 2; ++k) {
        const int ci0 = 2 * k;
        const int ci1 = ci0 + 1;

        load_rows(B, base, ci1, full);          // prefetch odd ci
        __builtin_amdgcn_sched_barrier(0);      // don't sink the prefetch
        compute_ci(acc, A, w, ci0);             // 576 FMAs hide B's latency

        if (k < CIN / 2 - 1)
            load_rows(A, base, ci0 + 2, full);  // prefetch next even ci
        __builtin_amdgcn_sched_barrier(0);
        compute_ci(acc, B, w, ci1);             // hides A's latency
    }

    // Epilogue. Even rows (oh) are 16B-aligned at ow (2046^2 = 0 mod 4,
    // oh*2046 = 0 mod 4 for even oh); odd rows are 8B-aligned.
    #pragma unroll
    for (int co = 0; co < COUT; ++co) {
        float* o0 = out + ((size_t)co * H_OUT + (size_t)oh) * W_OUT + ow;
        float* o1 = o0 + W_OUT;
        if (full) {
            *reinterpret_cast<float4*>(o0) =
                make_float4(acc[0][co][0], acc[0][co][1], acc[0][co][2], acc[0][co][3]);
            *reinterpret_cast<float2*>(o1)     = make_float2(acc[1][co][0], acc[1][co][1]);
            *reinterpret_cast<float2*>(o1 + 2) = make_float2(acc[1][co][2], acc[1][co][3]);
        } else {
            *reinterpret_cast<float2*>(o0) = make_float2(acc[0][co][0], acc[0][co][1]);
            *reinterpret_cast<float2*>(o1) = make_float2(acc[1][co][0], acc[1][co][1]);
        }
    }
}

extern "C" void kernel_launch(void* const* d_in, const int* in_sizes, int n_in,
                              void* d_out, int out_size, void* d_ws, size_t ws_size,
                              hipStream_t stream) {
    const float* x = (const float*)d_in[0];
    const float* w = (const float*)d_in[1];
    float* out = (float*)d_out;

    const int total_threads = NGROUPS * TPR;        // 1023 * 512 = 523,776
    const int block = 256;
    const int grid = total_threads / block;         // 2046 exactly

    conv3x3_v3<<<grid, block, 0, stream>>>(x, w, out);
}